// Round 6
// baseline (495.163 us; speedup 1.0000x reference)
//
#include <hip/hip_runtime.h>
#include <hip/hip_bf16.h>

using bf16 = __hip_bfloat16;
typedef __attribute__((ext_vector_type(8))) short bf16x8;
typedef __attribute__((ext_vector_type(4))) float f32x4;

static constexpr int TB  = 4;
static constexpr int TS  = 1024;
static constexpr int TD  = 1024;
static constexpr int TNH = 16;
static constexpr int TDH = 64;
static constexpr int TDI = 4096;

enum { FRELU = 1, FRESF = 2, FRESB = 4, FQKV = 16, FP32S = 32 };

__device__ __forceinline__ void gll16(const bf16* g, bf16* l)
{
    __builtin_amdgcn_global_load_lds(
        (const __attribute__((address_space(1))) void*)g,
        (__attribute__((address_space(3))) void*)l, 16, 0, 0);
}

// ---------------- fallback ----------------
__global__ __launch_bounds__(256) void zero_out_k(float* __restrict__ out, long n)
{
    long i = (long)blockIdx.x * 256 + threadIdx.x;
    if (i < n) out[i] = 0.0f;
}

// ---------------- fp32 -> bf16, 8/thread, two tensors ----------------
__global__ __launch_bounds__(256) void convert2_f2b(const float* __restrict__ a,
                                                    const float* __restrict__ b,
                                                    bf16* __restrict__ oa,
                                                    bf16* __restrict__ ob, long n)
{
    const float* src = blockIdx.y ? b : a;
    bf16* dst = blockIdx.y ? ob : oa;
    long i = ((long)blockIdx.x * 256 + threadIdx.x) * 8;
    if (i >= n) return;
    float4 f0 = *(const float4*)(src + i);
    float4 f1 = *(const float4*)(src + i + 4);
    bf16 t[8] = {__float2bfloat16(f0.x), __float2bfloat16(f0.y),
                 __float2bfloat16(f0.z), __float2bfloat16(f0.w),
                 __float2bfloat16(f1.x), __float2bfloat16(f1.y),
                 __float2bfloat16(f1.z), __float2bfloat16(f1.w)};
    *(bf16x8*)(dst + i) = *(bf16x8*)t;
}

// ---------------- transpose fp32 [R,C] -> bf16 [C,R] ----------------
__global__ __launch_bounds__(256) void transpose_f2b(const float* __restrict__ in,
                                                     bf16* __restrict__ out,
                                                     int R, int C)
{
    __shared__ float tile[32][33];
    int c0 = blockIdx.x * 32, r0 = blockIdx.y * 32;
    int tx = threadIdx.x & 31, ty = threadIdx.x >> 5;
#pragma unroll
    for (int dy = 0; dy < 32; dy += 8)
        tile[ty + dy][tx] = in[(long)(r0 + ty + dy) * C + (c0 + tx)];
    __syncthreads();
#pragma unroll
    for (int dy = 0; dy < 32; dy += 8)
        out[(long)(c0 + ty + dy) * R + (r0 + tx)] = __float2bfloat16(tile[tx][ty + dy]);
}

// ---------------- 5x square D x D transpose ----------------
__global__ __launch_bounds__(256) void transpose5_f2b(const float* __restrict__ p0,
                                                      const float* __restrict__ p1,
                                                      const float* __restrict__ p2,
                                                      const float* __restrict__ p3,
                                                      const float* __restrict__ p4,
                                                      bf16* __restrict__ dstBase)
{
    __shared__ float tile[32][33];
    const int D = TD;
    int z = blockIdx.z;
    const float* in = (z == 0) ? p0 : (z == 1) ? p1 : (z == 2) ? p2 : (z == 3) ? p3 : p4;
    bf16* out = dstBase + (long)z * D * D;
    int c0 = blockIdx.x * 32, r0 = blockIdx.y * 32;
    int tx = threadIdx.x & 31, ty = threadIdx.x >> 5;
#pragma unroll
    for (int dy = 0; dy < 32; dy += 8)
        tile[ty + dy][tx] = in[(long)(r0 + ty + dy) * D + (c0 + tx)];
    __syncthreads();
#pragma unroll
    for (int dy = 0; dy < 32; dy += 8)
        out[(long)(c0 + ty + dy) * D + (r0 + tx)] = __float2bfloat16(tile[tx][ty + dy]);
}

// ---------------- transpose V [B,S,NH*DH] -> VT [B,NH,DH,S] ----------------
__global__ __launch_bounds__(256) void transpose_v(const bf16* __restrict__ V,
                                                   bf16* __restrict__ VT)
{
    __shared__ bf16 tile[32][33];
    int bn = blockIdx.z;
    int b = bn >> 4, n = bn & 15;
    const bf16* src = V + ((long)b * TS) * (TNH * TDH) + n * TDH;
    bf16* dst = VT + (long)bn * TDH * TS;
    int s0 = blockIdx.x * 32, d0 = blockIdx.y * 32;
    int tx = threadIdx.x & 31, ty = threadIdx.x >> 5;
#pragma unroll
    for (int dy = 0; dy < 32; dy += 8)
        tile[ty + dy][tx] = src[(long)(s0 + ty + dy) * (TNH * TDH) + (d0 + tx)];
    __syncthreads();
#pragma unroll
    for (int dy = 0; dy < 32; dy += 8)
        dst[(long)(d0 + ty + dy) * TS + (s0 + tx)] = tile[tx][ty + dy];
}

// ---------------- m97-style NT bf16 MFMA GEMM ----------------
// FP32S: grid.y = K-split index z; A/Bt advance z*sAz/sBz along K; fp32 partials
// go to plane z chosen from {Cfp, C0, C2, C3} (reduced later in layernorm_f).
#define BM 128
#define BKK 32

template<int BNT>
__global__ __launch_bounds__(256) void gemm_k(
    const bf16* __restrict__ A, long lda, long sAz,
    const bf16* __restrict__ Bt, long ldb, long sBz,
    bf16* __restrict__ C0, bf16* __restrict__ C2, bf16* __restrict__ C3,
    float* __restrict__ Cfp,
    long ldc, long sCz,
    const float* __restrict__ bias,
    const float* __restrict__ residf, const bf16* __restrict__ residb,
    int N, int K, int GY, int mode)
{
    constexpr int WNW = BNT / 2;
    constexpr int FRJ = WNW / 16;
    constexpr int BCH = BNT / 64;

    __shared__ bf16 As[BM * BKK];
    __shared__ bf16 Bs[BNT * BKK];

    const int z = blockIdx.y;
    A  += (long)z * sAz;
    Bt += (long)z * sBz;
    const long coff = (long)z * sCz;

    long l = blockIdx.x;
    const int ty = (int)(l % GY);
    const int tx = (int)(l / GY);
    const int row0 = ty * BM;
    const int col0 = tx * BNT;

    const int tid  = threadIdx.x;
    const int lane = tid & 63;
    const int wave = tid >> 6;
    const int wm = (wave & 1) * 64;
    const int wn = (wave >> 1) * WNW;
    const int lr = lane & 15;
    const int lk = (lane >> 4) << 3;

    const int sr  = lane >> 2;
    const int skc = (lane & 3) << 3;

    f32x4 acc[4][FRJ] = {};

    for (int k0 = 0; k0 < K; k0 += BKK) {
#pragma unroll
        for (int c = 0; c < 2; ++c) {
            int ch = wave * 2 + c;
            gll16(A + (long)(row0 + ch * 16 + sr) * lda + (k0 + skc), &As[ch * 512]);
        }
#pragma unroll
        for (int c = 0; c < BCH; ++c) {
            int ch = wave * BCH + c;
            gll16(Bt + (long)(col0 + ch * 16 + sr) * ldb + (k0 + skc), &Bs[ch * 512]);
        }
        __syncthreads();

        bf16x8 af[4], bfv[FRJ];
#pragma unroll
        for (int t = 0; t < 4; ++t)
            af[t] = *(const bf16x8*)(&As[(wm + t * 16 + lr) * BKK + lk]);
#pragma unroll
        for (int t = 0; t < FRJ; ++t)
            bfv[t] = *(const bf16x8*)(&Bs[(wn + t * 16 + lr) * BKK + lk]);
#pragma unroll
        for (int i = 0; i < 4; ++i)
#pragma unroll
            for (int j = 0; j < FRJ; ++j)
                acc[i][j] = __builtin_amdgcn_mfma_f32_16x16x32_bf16(
                    af[i], bfv[j], acc[i][j], 0, 0, 0);
        __syncthreads();
    }

    const int lq = (lane >> 4) << 2;
    float* Pfp = (mode & FP32S)
        ? ((z == 0) ? Cfp : (z == 1) ? (float*)C0 : (z == 2) ? (float*)C2 : (float*)C3)
        : nullptr;
#pragma unroll
    for (int i = 0; i < 4; ++i) {
#pragma unroll
        for (int j = 0; j < FRJ; ++j) {
#pragma unroll
            for (int rg = 0; rg < 4; ++rg) {
                int mrow = row0 + wm + i * 16 + lq + rg;
                int ncol = col0 + wn + j * 16 + lr;
                float v = acc[i][j][rg];
                long rbase = (long)mrow * ldc;
                if (mode & FP32S) {
                    Pfp[rbase + ncol] = v;
                    continue;
                }
                if (mode & FQKV) {
                    if (ncol < 1024) {
                        C0[rbase + ncol] = __float2bfloat16(v + bias[ncol]);
                    } else if (ncol < 2048) {
                        C2[rbase + ncol - 1024] = __float2bfloat16(v);
                    } else {
                        C3[rbase + ncol - 2048] = __float2bfloat16(v);
                    }
                    continue;
                }
                if (bias)          v += bias[ncol];
                if (mode & FRELU)  v = fmaxf(v, 0.0f);
                if (mode & FRESF)  v += residf[rbase + ncol];
                if (mode & FRESB)  v += __bfloat162float(residb[rbase + ncol]);
                C0[coff + rbase + ncol] = __float2bfloat16(v);
            }
        }
    }
}

// ---------------- fused flash attention with Transformer-XL rel-shift ----------------
__global__ __launch_bounds__(256, 1) void flash_attn(
    const bf16* __restrict__ Qw, const bf16* __restrict__ Kb,
    const bf16* __restrict__ RRb, const bf16* __restrict__ VT,
    const float* __restrict__ wbias, const float* __restrict__ rbias,
    bf16* __restrict__ Oa)
{
    const int S = TS, D = TD;
    __shared__ bf16 Ks[128 * 64];
    __shared__ bf16 RRs[256 * 64];
    __shared__ bf16 VTs[64 * 128];
    __shared__ bf16 SCR[4][32 * 161];

    const int bx = blockIdx.x;
    const int irev = bx >> 6, bn = bx & 63;
    const int it = 7 - irev;
    const int i0 = it * 128;
    const int b = bn >> 4, n = bn & 15;

    const int tid = threadIdx.x, lane = tid & 63, wave = tid >> 6;
    const int dw = wave * 32;
    const int l15 = lane & 15, lq = lane >> 4;
    const int sr8 = lane >> 3, sc8 = lane & 7;
    const int vr4 = lane >> 4, vc16 = lane & 15;

    bf16x8 afw[2][2], afr[2][2];
#pragma unroll
    for (int m = 0; m < 2; ++m)
#pragma unroll
        for (int ks = 0; ks < 2; ++ks) {
            const bf16* qp = Qw + ((long)(b * S + i0 + dw + 16 * m + l15)) * D
                             + n * 64 + ks * 32 + lq * 8;
            afw[m][ks] = *(const bf16x8*)qp;
            bf16 tmp[8];
#pragma unroll
            for (int jj = 0; jj < 8; ++jj) {
                int di_ = n * 64 + ks * 32 + lq * 8 + jj;
                float f = __bfloat162float(((const bf16*)&afw[m][ks])[jj])
                          + rbias[di_] - wbias[di_];
                tmp[jj] = __float2bfloat16(f);
            }
            afr[m][ks] = *(bf16x8*)tmp;
        }

    float mst[2][4], lst[2][4];
    f32x4 Oacc[2][4] = {};
#pragma unroll
    for (int m = 0; m < 2; ++m)
#pragma unroll
        for (int rg = 0; rg < 4; ++rg) { mst[m][rg] = -1e30f; lst[m][rg] = 0.0f; }

    bf16* scr = &SCR[wave][0];
    const int cofs = 96 - dw;

    for (int jt = 0; jt <= it; ++jt) {
        const int j0 = jt * 128;
        const int cT0 = S - 1 + j0 - i0 - 127;

#pragma unroll
        for (int c = 0; c < 4; ++c) {
            int ch = wave * 4 + c;
            int row = ch * 8 + sr8;
            int cbs = sc8 ^ (sr8 & 7);
            gll16(Kb + ((long)(b * S + j0 + row)) * D + n * 64 + cbs * 8, &Ks[ch * 512]);
        }
#pragma unroll
        for (int c = 0; c < 8; ++c) {
            int ch = wave * 8 + c;
            int row = ch * 8 + sr8;
            int grow = cT0 + row; if (grow > S - 1) grow = S - 1;
            int cbs = sc8 ^ (sr8 & 7);
            gll16(RRb + ((long)(b * S + grow)) * D + n * 64 + cbs * 8, &RRs[ch * 512]);
        }
#pragma unroll
        for (int c = 0; c < 4; ++c) {
            int ch = wave * 4 + c;
            int row = ch * 4 + vr4;
            int cbs = vc16 ^ (row & 15);
            gll16(VT + ((long)(bn * 64 + row)) * S + j0 + cbs * 8, &VTs[ch * 512]);
        }
        __syncthreads();

        f32x4 bd[2][10] = {};
#pragma unroll
        for (int ks = 0; ks < 2; ++ks) {
            bf16x8 bfr[10];
#pragma unroll
            for (int nf = 0; nf < 10; ++nf) {
                int row = cofs + nf * 16 + l15;
                int cb = ks * 4 + lq;
                bfr[nf] = *(const bf16x8*)(&RRs[row * 64 + (cb ^ (row & 7)) * 8]);
            }
#pragma unroll
            for (int m = 0; m < 2; ++m)
#pragma unroll
                for (int nf = 0; nf < 10; ++nf)
                    bd[m][nf] = __builtin_amdgcn_mfma_f32_16x16x32_bf16(
                        afr[m][ks], bfr[nf], bd[m][nf], 0, 0, 0);
        }
#pragma unroll
        for (int m = 0; m < 2; ++m)
#pragma unroll
            for (int nf = 0; nf < 10; ++nf)
#pragma unroll
                for (int rg = 0; rg < 4; ++rg) {
                    int ldi = lq * 4 + rg + 16 * m;
                    scr[ldi * 161 + nf * 16 + l15] = __float2bfloat16(bd[m][nf][rg]);
                }

        f32x4 ac[2][8] = {};
#pragma unroll
        for (int ks = 0; ks < 2; ++ks) {
            bf16x8 bk[8];
#pragma unroll
            for (int nf = 0; nf < 8; ++nf) {
                int row = nf * 16 + l15;
                int cb = ks * 4 + lq;
                bk[nf] = *(const bf16x8*)(&Ks[row * 64 + (cb ^ (row & 7)) * 8]);
            }
#pragma unroll
            for (int m = 0; m < 2; ++m)
#pragma unroll
                for (int nf = 0; nf < 8; ++nf)
                    ac[m][nf] = __builtin_amdgcn_mfma_f32_16x16x32_bf16(
                        afw[m][ks], bk[nf], ac[m][nf], 0, 0, 0);
        }

        const bool diag = (jt == it);
#pragma unroll
        for (int m = 0; m < 2; ++m)
#pragma unroll
            for (int nf = 0; nf < 8; ++nf)
#pragma unroll
                for (int rg = 0; rg < 4; ++rg) {
                    int ldi = lq * 4 + rg + 16 * m;
                    int col = nf * 16 + l15;
                    float bdv = __bfloat162float(scr[ldi * 161 + (col + 31 - ldi)]);
                    float s = (ac[m][nf][rg] + bdv) * 0.125f;
                    if (diag && (col > dw + ldi)) s = -1e30f;
                    ac[m][nf][rg] = s;
                }

        float alpha[2][4];
#pragma unroll
        for (int m = 0; m < 2; ++m)
#pragma unroll
            for (int rg = 0; rg < 4; ++rg) {
                float v = -1e30f;
#pragma unroll
                for (int nf = 0; nf < 8; ++nf) v = fmaxf(v, ac[m][nf][rg]);
                for (int o = 8; o; o >>= 1) v = fmaxf(v, __shfl_xor(v, o));
                float mn = fmaxf(mst[m][rg], v);
                alpha[m][rg] = __expf(mst[m][rg] - mn);
                mst[m][rg] = mn;
            }
#pragma unroll
        for (int m = 0; m < 2; ++m)
#pragma unroll
            for (int nf = 0; nf < 8; ++nf)
#pragma unroll
                for (int rg = 0; rg < 4; ++rg)
                    ac[m][nf][rg] = __expf(ac[m][nf][rg] - mst[m][rg]);
#pragma unroll
        for (int m = 0; m < 2; ++m)
#pragma unroll
            for (int rg = 0; rg < 4; ++rg) {
                float sv = 0.0f;
#pragma unroll
                for (int nf = 0; nf < 8; ++nf) sv += ac[m][nf][rg];
                for (int o = 8; o; o >>= 1) sv += __shfl_xor(sv, o);
                lst[m][rg] = lst[m][rg] * alpha[m][rg] + sv;
            }
#pragma unroll
        for (int m = 0; m < 2; ++m)
#pragma unroll
            for (int nf = 0; nf < 4; ++nf)
#pragma unroll
                for (int rg = 0; rg < 4; ++rg)
                    Oacc[m][nf][rg] *= alpha[m][rg];

#pragma unroll
        for (int m = 0; m < 2; ++m)
#pragma unroll
            for (int nf = 0; nf < 8; ++nf)
#pragma unroll
                for (int rg = 0; rg < 4; ++rg) {
                    int ldi = lq * 4 + rg + 16 * m;
                    scr[ldi * 136 + nf * 16 + l15] = __float2bfloat16(ac[m][nf][rg]);
                }
#pragma unroll
        for (int ks2 = 0; ks2 < 4; ++ks2) {
            bf16x8 pa[2];
#pragma unroll
            for (int m = 0; m < 2; ++m)
                pa[m] = *(const bf16x8*)(&scr[(16 * m + l15) * 136 + ks2 * 32 + lq * 8]);
            bf16x8 vb[4];
#pragma unroll
            for (int nf = 0; nf < 4; ++nf) {
                int row = nf * 16 + l15;
                int cb = ks2 * 4 + lq;
                vb[nf] = *(const bf16x8*)(&VTs[row * 128 + (cb ^ (row & 15)) * 8]);
            }
#pragma unroll
            for (int m = 0; m < 2; ++m)
#pragma unroll
                for (int nf = 0; nf < 4; ++nf)
                    Oacc[m][nf] = __builtin_amdgcn_mfma_f32_16x16x32_bf16(
                        pa[m], vb[nf], Oacc[m][nf], 0, 0, 0);
        }
        __syncthreads();
    }

#pragma unroll
    for (int m = 0; m < 2; ++m)
#pragma unroll
        for (int rg = 0; rg < 4; ++rg) {
            float inv = 1.0f / lst[m][rg];
#pragma unroll
            for (int nf = 0; nf < 4; ++nf) {
                int row = i0 + dw + lq * 4 + rg + 16 * m;
                int col = nf * 16 + l15;
                Oa[((long)(b * S + row)) * D + n * 64 + col] =
                    __float2bfloat16(Oacc[m][nf][rg] * inv);
            }
        }
}

// ---------------- fused partial-sum (2 or 4 planes) + bias/residual + LayerNorm ----------------
__global__ __launch_bounds__(256) void layernorm_f(const float* __restrict__ A0,
                                                   const float* __restrict__ A1,
                                                   const float* __restrict__ A2,
                                                   const float* __restrict__ A3,
                                                   const float* __restrict__ bias,
                                                   const float* __restrict__ residf,
                                                   const bf16* __restrict__ residb,
                                                   const float* __restrict__ g,
                                                   const float* __restrict__ beta,
                                                   float* __restrict__ Yf,
                                                   bf16* __restrict__ Yb)
{
    const int D = TD;
    long row = blockIdx.x;
    int tid = threadIdx.x;
    int wave = tid >> 6;

    float v[4], s = 0.0f;
#pragma unroll
    for (int it = 0; it < 4; ++it) {
        int c = tid + it * 256;
        float x = A0[row * D + c] + A1[row * D + c];
        if (A2) x += A2[row * D + c];
        if (A3) x += A3[row * D + c];
        if (bias)   x += bias[c];
        if (residf) x += residf[row * D + c];
        if (residb) x += __bfloat162float(residb[row * D + c]);
        v[it] = x; s += x;
    }
    for (int off = 32; off; off >>= 1) s += __shfl_xor(s, off);
    __shared__ float sm[8];
    if ((tid & 63) == 0) sm[wave] = s;
    __syncthreads();
    float mean = (sm[0] + sm[1] + sm[2] + sm[3]) * (1.0f / D);

    float var = 0.0f;
#pragma unroll
    for (int it = 0; it < 4; ++it) { float d = v[it] - mean; var += d * d; }
    for (int off = 32; off; off >>= 1) var += __shfl_xor(var, off);
    if ((tid & 63) == 0) sm[4 + wave] = var;
    __syncthreads();
    var = (sm[4] + sm[5] + sm[6] + sm[7]) * (1.0f / D);
    float rinv = rsqrtf(var + 1e-5f);

#pragma unroll
    for (int it = 0; it < 4; ++it) {
        int c = tid + it * 256;
        float o = (v[it] - mean) * rinv * g[c] + beta[c];
        if (Yf) Yf[row * D + c] = o;
        if (Yb) Yb[row * D + c] = __float2bfloat16(o);
    }
}

extern "C" void kernel_launch(void* const* d_in, const int* in_sizes, int n_in,
                              void* d_out, int out_size, void* d_ws, size_t ws_size,
                              hipStream_t stream)
{
    const float* w      = (const float*)d_in[0];
    const float* r      = (const float*)d_in[1];
    const float* w_bias = (const float*)d_in[2];
    const float* r_bias = (const float*)d_in[3];
    const float* Wq     = (const float*)d_in[4];
    const float* Wk     = (const float*)d_in[5];
    const float* Wv     = (const float*)d_in[6];
    const float* Wr     = (const float*)d_in[7];
    const float* Wo     = (const float*)d_in[8];
    const float* ln1_g  = (const float*)d_in[9];
    const float* ln1_b  = (const float*)d_in[10];
    const float* W1     = (const float*)d_in[11];
    const float* b1     = (const float*)d_in[12];
    const float* W2     = (const float*)d_in[13];
    const float* b2     = (const float*)d_in[14];
    const float* ln2_g  = (const float*)d_in[15];
    const float* ln2_b  = (const float*)d_in[16];
    float* out = (float*)d_out;

    const int  B = TB, S = TS, D = TD, NH = TNH, DH = TDH, DI = TDI;
    const long MS = (long)B * S;
    const long ND = (long)MS * D;

    char* base = (char*)d_ws;
    size_t off = 0;
    auto alloc = [&](size_t bytes) -> void* {
        void* p = base + off;
        off += (bytes + 255) & ~(size_t)255;
        return p;
    };
    bf16* wqT  = (bf16*)alloc(2UL * D * D);   // wqT..w1T contiguous: dead 18 MB at W2 time
    bf16* wkT  = (bf16*)alloc(2UL * D * D);
    bf16* wvT  = (bf16*)alloc(2UL * D * D);
    bf16* wrT  = (bf16*)alloc(2UL * D * D);
    bf16* woT  = (bf16*)alloc(2UL * D * D);
    bf16* w1T  = (bf16*)alloc(2UL * D * DI);
    bf16* w2T  = (bf16*)alloc(2UL * DI * D);
    bf16* bufA = (bf16*)alloc(2UL * ND);            // w_bf -> attn_vec
    bf16* bufB = (bf16*)alloc(2UL * ND);            // r_bf -> x_bf
    bf16* Qw   = (bf16*)alloc(2UL * ND);            // Qw..VT (32 MB) -> fp32 partials p0,p1
    bf16* Kb   = (bf16*)alloc(2UL * ND);
    bf16* RRb  = (bf16*)alloc(2UL * ND);
    bf16* VT   = (bf16*)alloc(2UL * ND);
    bf16* R0   = (bf16*)alloc(2UL * MS * DI);       // Vb -> h (32 MB)
    size_t need = off;
    (void)in_sizes; (void)n_in; (void)out_size;

    if (ws_size < need) {
        zero_out_k<<<dim3((unsigned)((ND + 255) / 256)), 256, 0, stream>>>(out, ND);
        return;
    }

    bf16* w_bf = bufA;  bf16* attn_vec = bufA;
    bf16* r_bf = bufB;  bf16* x_bf     = bufB;
    bf16* Vb   = R0;    bf16* h        = R0;
    // fp32 partial planes (each MS*D*4 = 16 MB), all dead regions at their use time:
    float* p0 = (float*)Qw;    // spans Qw+Kb
    float* p1 = (float*)RRb;   // spans RRb+VT
    float* p2 = (float*)wqT;   // spans wqT..w1T (18 MB dead after W1; excludes w2T)
    float* p3 = out;           // reduced in-place by LN2 (reads-before-writes per row)

    auto gemm128 = [&](const bf16* A, const bf16* Bt,
                       bf16* C0, bf16* C2, bf16* C3, long ldc,
                       const float* bias, const float* rf, const bf16* rb,
                       int M, int N, int K, int mode) {
        int GY = M / BM, GX = N / 128;
        gemm_k<128><<<dim3((unsigned)(GX * GY), 1), 256, 0, stream>>>(
            A, K, 0, Bt, K, 0, C0, C2, C3, nullptr, ldc, 0, bias, rf, rb, N, K, GY, mode);
    };
    auto gemm64 = [&](const bf16* A, const bf16* Bt, bf16* C0, long ldc,
                      const float* bias, const float* rf, const bf16* rb,
                      int M, int N, int K, int mode) {
        int GY = M / BM, GX = N / 64;
        gemm_k<64><<<dim3((unsigned)(GX * GY), 1), 256, 0, stream>>>(
            A, K, 0, Bt, K, 0, C0, nullptr, nullptr, nullptr, ldc, 0, bias, rf, rb,
            N, K, GY, mode);
    };
    // split-K (2 or 4), 128x128 tile, fp32 partial planes q0..q3
    auto gemmSK = [&](const bf16* A, long lda, const bf16* Bt, long ldb,
                      float* q0, float* q1, float* q2, float* q3,
                      int M, int N, int K, int split) {
        int GY = M / BM, GX = N / 128;
        int Kh = K / split;
        gemm_k<128><<<dim3((unsigned)(GX * GY), split), 256, 0, stream>>>(
            A, lda, Kh, Bt, ldb, Kh, (bf16*)q1, (bf16*)q2, (bf16*)q3, q0,
            N, 0, nullptr, nullptr, nullptr, N, Kh, GY, FP32S);
    };

    // ---- converts + weight transposes ----
    convert2_f2b<<<dim3((unsigned)(ND / (8 * 256)), 2), 256, 0, stream>>>(
        w, r, w_bf, r_bf, ND);
    transpose5_f2b<<<dim3(D / 32, D / 32, 5), 256, 0, stream>>>(
        Wq, Wk, Wv, Wr, Wo, wqT);
    transpose_f2b<<<dim3(DI / 32, D / 32), 256, 0, stream>>>(W1, w1T, D, DI);
    transpose_f2b<<<dim3(D / 32, DI / 32), 256, 0, stream>>>(W2, w2T, DI, D);

    // ---- projections ----
    gemm128(w_bf, wqT, Qw, Kb, Vb, D, w_bias, nullptr, nullptr,
            (int)MS, 3 * D, D, FQKV);
    gemm64(r_bf, wrT, RRb, D, nullptr, nullptr, nullptr, (int)MS, D, D, 0);
    transpose_v<<<dim3(S / 32, DH / 32, B * NH), 256, 0, stream>>>(Vb, VT);

    // ---- fused flash attention ----
    flash_attn<<<dim3(512), 256, 0, stream>>>(Qw, Kb, RRb, VT, w_bias, r_bias, attn_vec);

    // ---- Wo (split-K2 -> p0,p1; Qw..VT dead) + fused LN1 ----
    gemmSK(attn_vec, D, woT, D, p0, p1, nullptr, nullptr, (int)MS, D, D, 2);
    layernorm_f<<<dim3((unsigned)MS), 256, 0, stream>>>(
        p0, p1, nullptr, nullptr, nullptr, w, nullptr, ln1_g, ln1_b, nullptr, x_bf);

    // ---- FFN ----
    gemm128(x_bf, w1T, h, nullptr, nullptr, DI, b1, nullptr, nullptr,
            (int)MS, DI, D, FRELU);
    gemmSK(h, DI, w2T, DI, p0, p1, p2, p3, (int)MS, D, DI, 4);
    layernorm_f<<<dim3((unsigned)MS), 256, 0, stream>>>(
        p0, p1, p2, p3, b2, nullptr, x_bf, ln2_g, ln2_b, out, nullptr);
}

// Round 7
// 493.297 us; speedup vs baseline: 1.0038x; 1.0038x over previous
//
#include <hip/hip_runtime.h>
#include <hip/hip_bf16.h>

using bf16 = __hip_bfloat16;
typedef __attribute__((ext_vector_type(8))) short bf16x8;
typedef __attribute__((ext_vector_type(4))) float f32x4;

static constexpr int TB  = 4;
static constexpr int TS  = 1024;
static constexpr int TD  = 1024;
static constexpr int TNH = 16;
static constexpr int TDH = 64;
static constexpr int TDI = 4096;

enum { FRELU = 1, FRESF = 2, FRESB = 4, FQKV = 16, FP32S = 32 };

__device__ __forceinline__ void gll16(const bf16* g, bf16* l)
{
    __builtin_amdgcn_global_load_lds(
        (const __attribute__((address_space(1))) void*)g,
        (__attribute__((address_space(3))) void*)l, 16, 0, 0);
}

// ---------------- fallback ----------------
__global__ __launch_bounds__(256) void zero_out_k(float* __restrict__ out, long n)
{
    long i = (long)blockIdx.x * 256 + threadIdx.x;
    if (i < n) out[i] = 0.0f;
}

// ---------------- fp32 -> bf16, 8/thread, two tensors ----------------
__global__ __launch_bounds__(256) void convert2_f2b(const float* __restrict__ a,
                                                    const float* __restrict__ b,
                                                    bf16* __restrict__ oa,
                                                    bf16* __restrict__ ob, long n)
{
    const float* src = blockIdx.y ? b : a;
    bf16* dst = blockIdx.y ? ob : oa;
    long i = ((long)blockIdx.x * 256 + threadIdx.x) * 8;
    if (i >= n) return;
    float4 f0 = *(const float4*)(src + i);
    float4 f1 = *(const float4*)(src + i + 4);
    bf16 t[8] = {__float2bfloat16(f0.x), __float2bfloat16(f0.y),
                 __float2bfloat16(f0.z), __float2bfloat16(f0.w),
                 __float2bfloat16(f1.x), __float2bfloat16(f1.y),
                 __float2bfloat16(f1.z), __float2bfloat16(f1.w)};
    *(bf16x8*)(dst + i) = *(bf16x8*)t;
}

// ---------------- transpose fp32 [R,C] -> bf16 [C,R] ----------------
__global__ __launch_bounds__(256) void transpose_f2b(const float* __restrict__ in,
                                                     bf16* __restrict__ out,
                                                     int R, int C)
{
    __shared__ float tile[32][33];
    int c0 = blockIdx.x * 32, r0 = blockIdx.y * 32;
    int tx = threadIdx.x & 31, ty = threadIdx.x >> 5;
#pragma unroll
    for (int dy = 0; dy < 32; dy += 8)
        tile[ty + dy][tx] = in[(long)(r0 + ty + dy) * C + (c0 + tx)];
    __syncthreads();
#pragma unroll
    for (int dy = 0; dy < 32; dy += 8)
        out[(long)(c0 + ty + dy) * R + (r0 + tx)] = __float2bfloat16(tile[tx][ty + dy]);
}

// ---------------- 5x square D x D transpose ----------------
__global__ __launch_bounds__(256) void transpose5_f2b(const float* __restrict__ p0,
                                                      const float* __restrict__ p1,
                                                      const float* __restrict__ p2,
                                                      const float* __restrict__ p3,
                                                      const float* __restrict__ p4,
                                                      bf16* __restrict__ dstBase)
{
    __shared__ float tile[32][33];
    const int D = TD;
    int z = blockIdx.z;
    const float* in = (z == 0) ? p0 : (z == 1) ? p1 : (z == 2) ? p2 : (z == 3) ? p3 : p4;
    bf16* out = dstBase + (long)z * D * D;
    int c0 = blockIdx.x * 32, r0 = blockIdx.y * 32;
    int tx = threadIdx.x & 31, ty = threadIdx.x >> 5;
#pragma unroll
    for (int dy = 0; dy < 32; dy += 8)
        tile[ty + dy][tx] = in[(long)(r0 + ty + dy) * D + (c0 + tx)];
    __syncthreads();
#pragma unroll
    for (int dy = 0; dy < 32; dy += 8)
        out[(long)(c0 + ty + dy) * D + (r0 + tx)] = __float2bfloat16(tile[tx][ty + dy]);
}

// ---------------- transpose V [B,S,NH*DH] -> VT [B,NH,DH,S] ----------------
__global__ __launch_bounds__(256) void transpose_v(const bf16* __restrict__ V,
                                                   bf16* __restrict__ VT)
{
    __shared__ bf16 tile[32][33];
    int bn = blockIdx.z;
    int b = bn >> 4, n = bn & 15;
    const bf16* src = V + ((long)b * TS) * (TNH * TDH) + n * TDH;
    bf16* dst = VT + (long)bn * TDH * TS;
    int s0 = blockIdx.x * 32, d0 = blockIdx.y * 32;
    int tx = threadIdx.x & 31, ty = threadIdx.x >> 5;
#pragma unroll
    for (int dy = 0; dy < 32; dy += 8)
        tile[ty + dy][tx] = src[(long)(s0 + ty + dy) * (TNH * TDH) + (d0 + tx)];
    __syncthreads();
#pragma unroll
    for (int dy = 0; dy < 32; dy += 8)
        dst[(long)(d0 + ty + dy) * TS + (s0 + tx)] = tile[tx][ty + dy];
}

// ---------------- m97-style NT bf16 MFMA GEMM ----------------
#define BM 128
#define BKK 32

template<int BNT>
__global__ __launch_bounds__(256) void gemm_k(
    const bf16* __restrict__ A, long lda, long sAz,
    const bf16* __restrict__ Bt, long ldb, long sBz,
    bf16* __restrict__ C0, bf16* __restrict__ C2, bf16* __restrict__ C3,
    float* __restrict__ Cfp,
    long ldc, long sCz,
    const float* __restrict__ bias,
    const float* __restrict__ residf, const bf16* __restrict__ residb,
    int N, int K, int GY, int mode)
{
    constexpr int WNW = BNT / 2;
    constexpr int FRJ = WNW / 16;
    constexpr int BCH = BNT / 64;

    __shared__ bf16 As[BM * BKK];
    __shared__ bf16 Bs[BNT * BKK];

    const int z = blockIdx.y;
    A  += (long)z * sAz;
    Bt += (long)z * sBz;
    const long coff = (long)z * sCz;

    long l = blockIdx.x;
    const int ty = (int)(l % GY);
    const int tx = (int)(l / GY);
    const int row0 = ty * BM;
    const int col0 = tx * BNT;

    const int tid  = threadIdx.x;
    const int lane = tid & 63;
    const int wave = tid >> 6;
    const int wm = (wave & 1) * 64;
    const int wn = (wave >> 1) * WNW;
    const int lr = lane & 15;
    const int lk = (lane >> 4) << 3;

    const int sr  = lane >> 2;
    const int skc = (lane & 3) << 3;

    f32x4 acc[4][FRJ] = {};

    for (int k0 = 0; k0 < K; k0 += BKK) {
#pragma unroll
        for (int c = 0; c < 2; ++c) {
            int ch = wave * 2 + c;
            gll16(A + (long)(row0 + ch * 16 + sr) * lda + (k0 + skc), &As[ch * 512]);
        }
#pragma unroll
        for (int c = 0; c < BCH; ++c) {
            int ch = wave * BCH + c;
            gll16(Bt + (long)(col0 + ch * 16 + sr) * ldb + (k0 + skc), &Bs[ch * 512]);
        }
        __syncthreads();

        bf16x8 af[4], bfv[FRJ];
#pragma unroll
        for (int t = 0; t < 4; ++t)
            af[t] = *(const bf16x8*)(&As[(wm + t * 16 + lr) * BKK + lk]);
#pragma unroll
        for (int t = 0; t < FRJ; ++t)
            bfv[t] = *(const bf16x8*)(&Bs[(wn + t * 16 + lr) * BKK + lk]);
#pragma unroll
        for (int i = 0; i < 4; ++i)
#pragma unroll
            for (int j = 0; j < FRJ; ++j)
                acc[i][j] = __builtin_amdgcn_mfma_f32_16x16x32_bf16(
                    af[i], bfv[j], acc[i][j], 0, 0, 0);
        __syncthreads();
    }

    const int lq = (lane >> 4) << 2;
    float* Pfp = (mode & FP32S)
        ? ((z == 0) ? Cfp : (z == 1) ? (float*)C0 : (z == 2) ? (float*)C2 : (float*)C3)
        : nullptr;
#pragma unroll
    for (int i = 0; i < 4; ++i) {
#pragma unroll
        for (int j = 0; j < FRJ; ++j) {
#pragma unroll
            for (int rg = 0; rg < 4; ++rg) {
                int mrow = row0 + wm + i * 16 + lq + rg;
                int ncol = col0 + wn + j * 16 + lr;
                float v = acc[i][j][rg];
                long rbase = (long)mrow * ldc;
                if (mode & FP32S) {
                    Pfp[rbase + ncol] = v;
                    continue;
                }
                if (mode & FQKV) {
                    if (ncol < 1024) {
                        C0[rbase + ncol] = __float2bfloat16(v + bias[ncol]);
                    } else if (ncol < 2048) {
                        C2[rbase + ncol - 1024] = __float2bfloat16(v);
                    } else {
                        C3[rbase + ncol - 2048] = __float2bfloat16(v);
                    }
                    continue;
                }
                if (bias)          v += bias[ncol];
                if (mode & FRELU)  v = fmaxf(v, 0.0f);
                if (mode & FRESF)  v += residf[rbase + ncol];
                if (mode & FRESB)  v += __bfloat162float(residb[rbase + ncol]);
                C0[coff + rbase + ncol] = __float2bfloat16(v);
            }
        }
    }
}

// ---------------- fused flash attention, j-tile = 64, 2 blocks/CU ----------------
// Grid: 512 = (i_rev*64 + b*16 + n). 4 waves, each owns 32 exclusive q-rows of a
// 128-row q-tile. LDS 64.3 KB -> 2 blocks/CU for latency hiding.
__global__ __launch_bounds__(256, 2) void flash_attn(
    const bf16* __restrict__ Qw, const bf16* __restrict__ Kb,
    const bf16* __restrict__ RRb, const bf16* __restrict__ VT,
    const float* __restrict__ wbias, const float* __restrict__ rbias,
    bf16* __restrict__ Oa)
{
    const int S = TS, D = TD;
    __shared__ bf16 Ks[64 * 64];         // K tile (rows j), swizzled cb^(row&7)
    __shared__ bf16 RRs[192 * 64];       // RR band rows, swizzled cb^(row&7)
    __shared__ bf16 VTs[64 * 64];        // V^T tile (rows d), swizzled cb^(row&7)
    __shared__ bf16 SCR[4][32 * 97];     // per-wave: BD band (stride 97) / P (stride 72)

    const int bx = blockIdx.x;
    const int irev = bx >> 6, bn = bx & 63;
    const int it = 7 - irev;
    const int i0 = it * 128;
    const int b = bn >> 4, n = bn & 15;

    const int tid = threadIdx.x, lane = tid & 63, wave = tid >> 6;
    const int dw = wave * 32;
    const int l15 = lane & 15, lq = lane >> 4;
    const int sr8 = lane >> 3, sc8 = lane & 7;     // staging: 8 rows x 64 cols / chunk
    const int cbs = sc8 ^ (sr8 & 7);

    // ---- loop-invariant Q fragments (A-layout: row=l15, k=lq*8+jj) ----
    bf16x8 afw[2][2], afr[2][2];
#pragma unroll
    for (int m = 0; m < 2; ++m)
#pragma unroll
        for (int ks = 0; ks < 2; ++ks) {
            const bf16* qp = Qw + ((long)(b * S + i0 + dw + 16 * m + l15)) * D
                             + n * 64 + ks * 32 + lq * 8;
            afw[m][ks] = *(const bf16x8*)qp;
            bf16 tmp[8];
#pragma unroll
            for (int jj = 0; jj < 8; ++jj) {
                int di_ = n * 64 + ks * 32 + lq * 8 + jj;
                float f = __bfloat162float(((const bf16*)&afw[m][ks])[jj])
                          + rbias[di_] - wbias[di_];
                tmp[jj] = __float2bfloat16(f);
            }
            afr[m][ks] = *(bf16x8*)tmp;
        }

    float mst[2][4], lst[2][4];
    f32x4 Oacc[2][4] = {};
#pragma unroll
    for (int m = 0; m < 2; ++m)
#pragma unroll
        for (int rg = 0; rg < 4; ++rg) { mst[m][rg] = -1e30f; lst[m][rg] = 0.0f; }

    bf16* scr = &SCR[wave][0];
    const int cofs = 96 - dw;      // wave's band start row within RRs

    const int njt = 2 * it + 2;
    for (int jt = 0; jt < njt; ++jt) {
        const int j0 = jt * 64;
        const int doff = j0 - i0;                  // mask: dj + doff > dw + ldi
        const int cT0 = S - 1 + j0 - i0 - 127;     // global rr row of RRs row 0 (>=0)

        // ---- stage K (8 chunks), RR band (24), VT (8); 2+6+2 per wave ----
#pragma unroll
        for (int c = 0; c < 2; ++c) {
            int ch = wave * 2 + c;
            int row = ch * 8 + sr8;
            gll16(Kb + ((long)(b * S + j0 + row)) * D + n * 64 + cbs * 8, &Ks[ch * 512]);
        }
#pragma unroll
        for (int c = 0; c < 6; ++c) {
            int ch = wave * 6 + c;
            int row = ch * 8 + sr8;
            int grow = cT0 + row; if (grow > S - 1) grow = S - 1;  // masked elems only
            gll16(RRb + ((long)(b * S + grow)) * D + n * 64 + cbs * 8, &RRs[ch * 512]);
        }
#pragma unroll
        for (int c = 0; c < 2; ++c) {
            int ch = wave * 2 + c;
            int row = ch * 8 + sr8;                  // d in [0,64)
            gll16(VT + ((long)(bn * 64 + row)) * S + j0 + cbs * 8, &VTs[ch * 512]);
        }
        __syncthreads();

        // ---- BD band (96 band-cols, 6 frags) ----
        f32x4 bd[2][6] = {};
#pragma unroll
        for (int ks = 0; ks < 2; ++ks) {
            bf16x8 bfr[6];
#pragma unroll
            for (int nf = 0; nf < 6; ++nf) {
                int row = cofs + nf * 16 + l15;
                int cb = ks * 4 + lq;
                bfr[nf] = *(const bf16x8*)(&RRs[row * 64 + (cb ^ (row & 7)) * 8]);
            }
#pragma unroll
            for (int m = 0; m < 2; ++m)
#pragma unroll
                for (int nf = 0; nf < 6; ++nf)
                    bd[m][nf] = __builtin_amdgcn_mfma_f32_16x16x32_bf16(
                        afr[m][ks], bfr[nf], bd[m][nf], 0, 0, 0);
        }
#pragma unroll
        for (int m = 0; m < 2; ++m)
#pragma unroll
            for (int nf = 0; nf < 6; ++nf)
#pragma unroll
                for (int rg = 0; rg < 4; ++rg) {
                    int ldi = lq * 4 + rg + 16 * m;
                    scr[ldi * 97 + nf * 16 + l15] = __float2bfloat16(bd[m][nf][rg]);
                }

        // ---- AC ----
        f32x4 ac[2][4] = {};
#pragma unroll
        for (int ks = 0; ks < 2; ++ks) {
            bf16x8 bk[4];
#pragma unroll
            for (int nf = 0; nf < 4; ++nf) {
                int row = nf * 16 + l15;
                int cb = ks * 4 + lq;
                bk[nf] = *(const bf16x8*)(&Ks[row * 64 + (cb ^ (row & 7)) * 8]);
            }
#pragma unroll
            for (int m = 0; m < 2; ++m)
#pragma unroll
                for (int nf = 0; nf < 4; ++nf)
                    ac[m][nf] = __builtin_amdgcn_mfma_f32_16x16x32_bf16(
                        afw[m][ks], bk[nf], ac[m][nf], 0, 0, 0);
        }

        // ---- shift-add + causal mask + scale ----
#pragma unroll
        for (int m = 0; m < 2; ++m)
#pragma unroll
            for (int nf = 0; nf < 4; ++nf)
#pragma unroll
                for (int rg = 0; rg < 4; ++rg) {
                    int ldi = lq * 4 + rg + 16 * m;
                    int col = nf * 16 + l15;                 // dj
                    float bdv = __bfloat162float(scr[ldi * 97 + (col + 31 - ldi)]);
                    float s = (ac[m][nf][rg] + bdv) * 0.125f;
                    if (col + doff > dw + ldi) s = -1e30f;
                    ac[m][nf][rg] = s;
                }

        // ---- online softmax ----
        float alpha[2][4];
#pragma unroll
        for (int m = 0; m < 2; ++m)
#pragma unroll
            for (int rg = 0; rg < 4; ++rg) {
                float v = -1e30f;
#pragma unroll
                for (int nf = 0; nf < 4; ++nf) v = fmaxf(v, ac[m][nf][rg]);
                for (int o = 8; o; o >>= 1) v = fmaxf(v, __shfl_xor(v, o));
                float mn = fmaxf(mst[m][rg], v);
                alpha[m][rg] = __expf(mst[m][rg] - mn);
                mst[m][rg] = mn;
            }
#pragma unroll
        for (int m = 0; m < 2; ++m)
#pragma unroll
            for (int nf = 0; nf < 4; ++nf)
#pragma unroll
                for (int rg = 0; rg < 4; ++rg)
                    ac[m][nf][rg] = __expf(ac[m][nf][rg] - mst[m][rg]);
#pragma unroll
        for (int m = 0; m < 2; ++m)
#pragma unroll
            for (int rg = 0; rg < 4; ++rg) {
                float sv = 0.0f;
#pragma unroll
                for (int nf = 0; nf < 4; ++nf) sv += ac[m][nf][rg];
                for (int o = 8; o; o >>= 1) sv += __shfl_xor(sv, o);
                lst[m][rg] = lst[m][rg] * alpha[m][rg] + sv;
            }
#pragma unroll
        for (int m = 0; m < 2; ++m)
#pragma unroll
            for (int nf = 0; nf < 4; ++nf)
#pragma unroll
                for (int rg = 0; rg < 4; ++rg)
                    Oacc[m][nf][rg] *= alpha[m][rg];

        // ---- P -> per-wave scratch (stride 72), then PV ----
#pragma unroll
        for (int m = 0; m < 2; ++m)
#pragma unroll
            for (int nf = 0; nf < 4; ++nf)
#pragma unroll
                for (int rg = 0; rg < 4; ++rg) {
                    int ldi = lq * 4 + rg + 16 * m;
                    scr[ldi * 72 + nf * 16 + l15] = __float2bfloat16(ac[m][nf][rg]);
                }
#pragma unroll
        for (int ks2 = 0; ks2 < 2; ++ks2) {
            bf16x8 pa[2];
#pragma unroll
            for (int m = 0; m < 2; ++m)
                pa[m] = *(const bf16x8*)(&scr[(16 * m + l15) * 72 + ks2 * 32 + lq * 8]);
            bf16x8 vb[4];
#pragma unroll
            for (int nf = 0; nf < 4; ++nf) {
                int row = nf * 16 + l15;
                int cb = ks2 * 4 + lq;
                vb[nf] = *(const bf16x8*)(&VTs[row * 64 + (cb ^ (row & 7)) * 8]);
            }
#pragma unroll
            for (int m = 0; m < 2; ++m)
#pragma unroll
                for (int nf = 0; nf < 4; ++nf)
                    Oacc[m][nf] = __builtin_amdgcn_mfma_f32_16x16x32_bf16(
                        pa[m], vb[nf], Oacc[m][nf], 0, 0, 0);
        }
        __syncthreads();
    }

#pragma unroll
    for (int m = 0; m < 2; ++m)
#pragma unroll
        for (int rg = 0; rg < 4; ++rg) {
            float inv = 1.0f / lst[m][rg];
#pragma unroll
            for (int nf = 0; nf < 4; ++nf) {
                int row = i0 + dw + lq * 4 + rg + 16 * m;
                int col = nf * 16 + l15;
                Oa[((long)(b * S + row)) * D + n * 64 + col] =
                    __float2bfloat16(Oacc[m][nf][rg] * inv);
            }
        }
}

// ---------------- fused partial-sum + bias/residual + LayerNorm ----------------
__global__ __launch_bounds__(256) void layernorm_f(const float* __restrict__ A0,
                                                   const float* __restrict__ A1,
                                                   const float* __restrict__ A2,
                                                   const float* __restrict__ A3,
                                                   const float* __restrict__ bias,
                                                   const float* __restrict__ residf,
                                                   const bf16* __restrict__ residb,
                                                   const float* __restrict__ g,
                                                   const float* __restrict__ beta,
                                                   float* __restrict__ Yf,
                                                   bf16* __restrict__ Yb)
{
    const int D = TD;
    long row = blockIdx.x;
    int tid = threadIdx.x;
    int wave = tid >> 6;

    float v[4], s = 0.0f;
#pragma unroll
    for (int it = 0; it < 4; ++it) {
        int c = tid + it * 256;
        float x = A0[row * D + c] + A1[row * D + c];
        if (A2) x += A2[row * D + c];
        if (A3) x += A3[row * D + c];
        if (bias)   x += bias[c];
        if (residf) x += residf[row * D + c];
        if (residb) x += __bfloat162float(residb[row * D + c]);
        v[it] = x; s += x;
    }
    for (int off = 32; off; off >>= 1) s += __shfl_xor(s, off);
    __shared__ float sm[8];
    if ((tid & 63) == 0) sm[wave] = s;
    __syncthreads();
    float mean = (sm[0] + sm[1] + sm[2] + sm[3]) * (1.0f / D);

    float var = 0.0f;
#pragma unroll
    for (int it = 0; it < 4; ++it) { float d = v[it] - mean; var += d * d; }
    for (int off = 32; off; off >>= 1) var += __shfl_xor(var, off);
    if ((tid & 63) == 0) sm[4 + wave] = var;
    __syncthreads();
    var = (sm[4] + sm[5] + sm[6] + sm[7]) * (1.0f / D);
    float rinv = rsqrtf(var + 1e-5f);

#pragma unroll
    for (int it = 0; it < 4; ++it) {
        int c = tid + it * 256;
        float o = (v[it] - mean) * rinv * g[c] + beta[c];
        if (Yf) Yf[row * D + c] = o;
        if (Yb) Yb[row * D + c] = __float2bfloat16(o);
    }
}

extern "C" void kernel_launch(void* const* d_in, const int* in_sizes, int n_in,
                              void* d_out, int out_size, void* d_ws, size_t ws_size,
                              hipStream_t stream)
{
    const float* w      = (const float*)d_in[0];
    const float* r      = (const float*)d_in[1];
    const float* w_bias = (const float*)d_in[2];
    const float* r_bias = (const float*)d_in[3];
    const float* Wq     = (const float*)d_in[4];
    const float* Wk     = (const float*)d_in[5];
    const float* Wv     = (const float*)d_in[6];
    const float* Wr     = (const float*)d_in[7];
    const float* Wo     = (const float*)d_in[8];
    const float* ln1_g  = (const float*)d_in[9];
    const float* ln1_b  = (const float*)d_in[10];
    const float* W1     = (const float*)d_in[11];
    const float* b1     = (const float*)d_in[12];
    const float* W2     = (const float*)d_in[13];
    const float* b2     = (const float*)d_in[14];
    const float* ln2_g  = (const float*)d_in[15];
    const float* ln2_b  = (const float*)d_in[16];
    float* out = (float*)d_out;

    const int  B = TB, S = TS, D = TD, NH = TNH, DH = TDH, DI = TDI;
    const long MS = (long)B * S;
    const long ND = (long)MS * D;

    char* base = (char*)d_ws;
    size_t off = 0;
    auto alloc = [&](size_t bytes) -> void* {
        void* p = base + off;
        off += (bytes + 255) & ~(size_t)255;
        return p;
    };
    bf16* wqT  = (bf16*)alloc(2UL * D * D);   // wqT..wvT contiguous = fused QKV B
    bf16* wkT  = (bf16*)alloc(2UL * D * D);
    bf16* wvT  = (bf16*)alloc(2UL * D * D);
    bf16* wrT  = (bf16*)alloc(2UL * D * D);
    bf16* woT  = (bf16*)alloc(2UL * D * D);
    bf16* w1T  = (bf16*)alloc(2UL * D * DI);
    bf16* w2T  = (bf16*)alloc(2UL * DI * D);
    bf16* bufA = (bf16*)alloc(2UL * ND);            // w_bf -> attn_vec
    bf16* bufB = (bf16*)alloc(2UL * ND);            // r_bf -> x_bf
    bf16* Qw   = (bf16*)alloc(2UL * ND);            // Qw..VT (32 MB) -> fp32 partials p0,p1
    bf16* Kb   = (bf16*)alloc(2UL * ND);
    bf16* RRb  = (bf16*)alloc(2UL * ND);
    bf16* VT   = (bf16*)alloc(2UL * ND);
    bf16* R0   = (bf16*)alloc(2UL * MS * DI);       // Vb -> h (32 MB)
    size_t need = off;
    (void)in_sizes; (void)n_in; (void)out_size;

    if (ws_size < need) {
        zero_out_k<<<dim3((unsigned)((ND + 255) / 256)), 256, 0, stream>>>(out, ND);
        return;
    }

    bf16* w_bf = bufA;  bf16* attn_vec = bufA;
    bf16* r_bf = bufB;  bf16* x_bf     = bufB;
    bf16* Vb   = R0;    bf16* h        = R0;
    float* p0 = (float*)Qw;    // spans Qw+Kb (dead after flash)
    float* p1 = (float*)RRb;   // spans RRb+VT (dead after flash)

    auto gemm128 = [&](const bf16* A, const bf16* Bt,
                       bf16* C0, bf16* C2, bf16* C3, long ldc,
                       const float* bias, const float* rf, const bf16* rb,
                       int M, int N, int K, int mode) {
        int GY = M / BM, GX = N / 128;
        gemm_k<128><<<dim3((unsigned)(GX * GY), 1), 256, 0, stream>>>(
            A, K, 0, Bt, K, 0, C0, C2, C3, nullptr, ldc, 0, bias, rf, rb, N, K, GY, mode);
    };
    auto gemm64 = [&](const bf16* A, const bf16* Bt, bf16* C0, long ldc,
                      const float* bias, const float* rf, const bf16* rb,
                      int M, int N, int K, int mode) {
        int GY = M / BM, GX = N / 64;
        gemm_k<64><<<dim3((unsigned)(GX * GY), 1), 256, 0, stream>>>(
            A, K, 0, Bt, K, 0, C0, nullptr, nullptr, nullptr, ldc, 0, bias, rf, rb,
            N, K, GY, mode);
    };
    // split-K2, 128x128 tile, fp32 partial planes q0,q1
    auto gemmSK2 = [&](const bf16* A, long lda, const bf16* Bt, long ldb,
                       float* q0, float* q1, int M, int N, int K) {
        int GY = M / BM, GX = N / 128;
        int Kh = K / 2;
        gemm_k<128><<<dim3((unsigned)(GX * GY), 2), 256, 0, stream>>>(
            A, lda, Kh, Bt, ldb, Kh, (bf16*)q1, nullptr, nullptr, q0,
            N, 0, nullptr, nullptr, nullptr, N, Kh, GY, FP32S);
    };

    // ---- converts + weight transposes ----
    convert2_f2b<<<dim3((unsigned)(ND / (8 * 256)), 2), 256, 0, stream>>>(
        w, r, w_bf, r_bf, ND);
    transpose5_f2b<<<dim3(D / 32, D / 32, 5), 256, 0, stream>>>(
        Wq, Wk, Wv, Wr, Wo, wqT);
    transpose_f2b<<<dim3(DI / 32, D / 32), 256, 0, stream>>>(W1, w1T, D, DI);
    transpose_f2b<<<dim3(D / 32, DI / 32), 256, 0, stream>>>(W2, w2T, DI, D);

    // ---- projections ----
    gemm128(w_bf, wqT, Qw, Kb, Vb, D, w_bias, nullptr, nullptr,
            (int)MS, 3 * D, D, FQKV);
    gemm64(r_bf, wrT, RRb, D, nullptr, nullptr, nullptr, (int)MS, D, D, 0);
    transpose_v<<<dim3(S / 32, DH / 32, B * NH), 256, 0, stream>>>(Vb, VT);

    // ---- fused flash attention (2 blocks/CU) ----
    flash_attn<<<dim3(512), 256, 0, stream>>>(Qw, Kb, RRb, VT, w_bias, r_bias, attn_vec);

    // ---- Wo (split-K2 -> p0,p1) + fused LN1 ----
    gemmSK2(attn_vec, D, woT, D, p0, p1, (int)MS, D, D);
    layernorm_f<<<dim3((unsigned)MS), 256, 0, stream>>>(
        p0, p1, nullptr, nullptr, nullptr, w, nullptr, ln1_g, ln1_b, nullptr, x_bf);

    // ---- FFN ----
    gemm128(x_bf, w1T, h, nullptr, nullptr, DI, b1, nullptr, nullptr,
            (int)MS, DI, D, FRELU);
    gemmSK2(h, DI, w2T, DI, p0, p1, (int)MS, D, DI);
    layernorm_f<<<dim3((unsigned)MS), 256, 0, stream>>>(
        p0, p1, nullptr, nullptr, b2, nullptr, x_bf, ln2_g, ln2_b, out, nullptr);
}